// Round 6
// baseline (126.963 us; speedup 1.0000x reference)
//
#include <hip/hip_runtime.h>
#include <math.h>

#define BROWS 512
#define SLEN  8192
#define NT    1024             // threads per block (16 waves)
#define NWRD  (SLEN / 32)      // 256 mask words per row
#define MWRD  (NWRD + 2)       // +1 guard word each side (window masks)

// distance (capped; >5 -> 99) to nearest set bit within +/-5 of position t
__device__ __forceinline__ int win_dist(const unsigned int* __restrict__ M, int t) {
    int sI = t + 27;                   // (t-5) + 32-bit guard offset
    int w  = sI >> 5;
    int off = sI & 31;
    unsigned long long val =
        ((unsigned long long)M[w] | ((unsigned long long)M[w + 1] << 32)) >> off;
    unsigned int win = (unsigned int)val & 0x7FFu;   // bit5 == position t
    if (win & 32u) return 0;
    unsigned int dn = win & 31u;          // bits 0..4 = t-5..t-1
    unsigned int up = (win >> 6) & 31u;   // bits 0..4 = t+1..t+5
    int d = 99;
    if (dn) d = 5 - (31 - __clz((int)dn));
    if (up) { int du = __ffs((int)up); if (du < d) d = du; }
    return d;
}

__device__ __forceinline__ float decay_pow(int d) {
    return (d == 1) ? 0.7f : (d == 2) ? 0.49f : (d == 3) ? 0.343f
         : (d == 4) ? 0.2401f : 0.16807f;
}

// ---- phase-1 step: argmax + CE + pack + ballot-publish masks ----
#define STEP(k, qv, lab, cev) {                                               \
    float m01 = fmaxf((qv).x, (qv).y), m23 = fmaxf((qv).z, (qv).w);           \
    float best = fmaxf(m01, m23);                                             \
    int pred = (best == (qv).x) ? 0 : (best == (qv).y) ? 1                    \
             : (best == (qv).z) ? 2 : 3;                                      \
    bool valid = ((lab) != -100);                                             \
    int l = valid ? ((lab) & 3) : 0;                                          \
    float se = __expf((qv).x - best) + __expf((qv).y - best) +                \
               __expf((qv).z - best) + __expf((qv).w - best);                 \
    float lse = best + __logf(se);                                            \
    float xl = (l == 0) ? (qv).x : (l == 1) ? (qv).y                          \
             : (l == 2) ? (qv).z : (qv).w;                                    \
    cev = valid ? (lse - xl) * ((l >= 2) ? 30.0f : 1.0f) : 0.0f;              \
    pkw |= (unsigned long long)(unsigned)(pred | (l << 2) | (valid ? 16 : 0)) \
           << (8 * (k));                                                      \
    unsigned long long bT2 = __ballot(valid && l == 2);                       \
    unsigned long long bP2 = __ballot(pred == 2);                             \
    unsigned long long bT3 = __ballot(valid && l == 3);                       \
    unsigned long long bP3 = __ballot(pred == 3);                             \
    unsigned long long bV  = __ballot(valid);                                 \
    unsigned long long bPM = __ballot(valid && (pred & 1));                   \
    unsigned long long bTM = __ballot(valid && (l & 1));                      \
    int wk = (k) * 32 + wid * 2;                                              \
    if (lane == 0) {                                                          \
        s_m[0][1 + wk] = (unsigned)bT2; s_m[1][1 + wk] = (unsigned)bP2;       \
        s_m[2][1 + wk] = (unsigned)bT3; s_m[3][1 + wk] = (unsigned)bP3;       \
        s_v[wk] = (unsigned)bV; s_pm[wk] = (unsigned)bPM;                     \
        s_tm[wk] = (unsigned)bTM;                                             \
    } else if (lane == 32) {                                                  \
        s_m[0][2 + wk] = (unsigned)(bT2 >> 32);                               \
        s_m[1][2 + wk] = (unsigned)(bP2 >> 32);                               \
        s_m[2][2 + wk] = (unsigned)(bT3 >> 32);                               \
        s_m[3][2 + wk] = (unsigned)(bP3 >> 32);                               \
        s_v[wk + 1] = (unsigned)(bV >> 32);                                   \
        s_pm[wk + 1] = (unsigned)(bPM >> 32);                                 \
        s_tm[wk + 1] = (unsigned)(bTM >> 32);                                 \
    }                                                                         \
    fl |= (bT2 ? 1u : 0u) | (bP2 ? 2u : 0u) | (bT3 ? 4u : 0u)                 \
        | (bP3 ? 8u : 0u);                                                    \
    cntw += (int)__popcll(bV);                                                \
}

// ---- phase-3 step: random-access carry lookup + window multipliers ----
#define P3(k, cev) {                                                          \
    int t = (k) * NT + tid;                                                   \
    unsigned pk = (unsigned)(pkw >> (8 * (k))) & 31u;                         \
    int pred = pk & 3, l = (pk >> 2) & 3;                                     \
    bool valid = (pk & 16) != 0;                                              \
    float m = 1.0f;                                                           \
    if (valid && (pred >= 2 || l >= 2)) {                                     \
        int w = t >> 5, b = t & 31;                                           \
        unsigned hi = s_v[w];                                                 \
        unsigned lo = (w > 0) ? s_v[w - 1] : 0u;                              \
        unsigned long long x = (((unsigned long long)hi) << 32) | lo;         \
        x &= (1ull << (b + 32)) - 1ull;                                       \
        int pm = 0, tm = 0;                                                   \
        if (x) {                                                              \
            int p = 63 - __clzll(x);                                          \
            int ww = w - 1 + (p >> 5); int pb = p & 31;                       \
            pm = (int)((s_pm[ww] >> pb) & 1u);                                \
            tm = (int)((s_tm[ww] >> pb) & 1u);                                \
        } else if (w >= 2) {      /* >=32-long invalid run: ~never */         \
            int ww = w - 2; unsigned xx = 0u;                                 \
            while (ww >= 0 && (xx = s_v[ww]) == 0u) --ww;                     \
            if (ww >= 0) { int pb = 31 - __clz((int)xx);                      \
                pm = (int)((s_pm[ww] >> pb) & 1u);                            \
                tm = (int)((s_tm[ww] >> pb) & 1u); }                          \
        }                                                                     \
        bool bad = (pred == 2 && pm == 0) || (pred == 3 && pm == 1);          \
        if (bad) m *= 100.0f;                                                 \
        bool good = (l == 2 && tm == 1 && pred == 2) ||                       \
                    (l == 3 && tm == 0 && pred == 3);                         \
        if (good) m *= 0.1f;                                                  \
    }                                                                         \
    if (pred >= 2) {                                                          \
        bool has = (pred == 2) ? hasT2 : hasT3;                               \
        if (!has) m *= 20.0f;                                                 \
        else {                                                                \
            int d = win_dist(s_m[(pred - 2) << 1], t);                        \
            m *= (d == 0) ? 0.1f : (d <= 5) ? decay_pow(d) : 10.0f;           \
        }                                                                     \
    }                                                                         \
    if (valid && l >= 2) {                                                    \
        bool has = (l == 2) ? hasP2 : hasP3;                                  \
        if (!has) m *= 3.0f;                                                  \
        else if (win_dist(s_m[1 + ((l - 2) << 1)], t) > 5) m *= 2.0f;         \
    }                                                                         \
    acc += (cev) * m;                                                         \
}

__global__ __launch_bounds__(NT, 4) void row_loss_kernel(
    const float* __restrict__ logits, const int* __restrict__ labels,
    double* __restrict__ psum, unsigned int* __restrict__ pcnt)
{
    __shared__ unsigned int s_m[4][MWRD];   // window masks: t2, p2, t3, p3
    __shared__ unsigned int s_v[NWRD];      // valid bitmask
    __shared__ unsigned int s_pm[NWRD];     // valid & (pred&1)
    __shared__ unsigned int s_tm[NWRD];     // valid & (lab&1)
    __shared__ unsigned int s_wfl[16];      // per-wave has-any flags
    __shared__ double       s_red[16];
    __shared__ int          s_redc[16];

    const int row  = blockIdx.x;
    const int tid  = threadIdx.x;
    const int lane = tid & 63;
    const int wid  = tid >> 6;

    // zero window-mask guard words only (interiors fully written by ballots)
    if (tid < 4) { s_m[tid][0] = 0u; s_m[tid][MWRD - 1] = 0u; }

    const float4* lg4 = (const float4*)logits + (size_t)row * SLEN;
    const int*    lb  = labels + (size_t)row * SLEN;

    // ---- Phase 1: coalesced strided loads (t = k*NT + tid) ----
    float4 q0 = lg4[0 * NT + tid], q1 = lg4[1 * NT + tid];
    float4 q2 = lg4[2 * NT + tid], q3 = lg4[3 * NT + tid];
    float4 q4 = lg4[4 * NT + tid], q5 = lg4[5 * NT + tid];
    float4 q6 = lg4[6 * NT + tid], q7 = lg4[7 * NT + tid];
    int la0 = lb[0 * NT + tid], la1 = lb[1 * NT + tid];
    int la2 = lb[2 * NT + tid], la3 = lb[3 * NT + tid];
    int la4 = lb[4 * NT + tid], la5 = lb[5 * NT + tid];
    int la6 = lb[6 * NT + tid], la7 = lb[7 * NT + tid];

    unsigned long long pkw = 0ull;
    unsigned int fl = 0u;
    int cntw = 0;
    float ce0, ce1, ce2, ce3, ce4, ce5, ce6, ce7;

    STEP(0, q0, la0, ce0); STEP(1, q1, la1, ce1);
    STEP(2, q2, la2, ce2); STEP(3, q3, la3, ce3);
    STEP(4, q4, la4, ce4); STEP(5, q5, la5, ce5);
    STEP(6, q6, la6, ce6); STEP(7, q7, la7, ce7);

    if (lane == 0) s_wfl[wid] = fl;
    __syncthreads();   // masks + flags visible

    // block-wide has-any flags: OR the 16 per-wave words (broadcast reads)
    uint4 f0 = *(const uint4*)(s_wfl + 0), f1 = *(const uint4*)(s_wfl + 4);
    uint4 f2 = *(const uint4*)(s_wfl + 8), f3 = *(const uint4*)(s_wfl + 12);
    unsigned int flags = f0.x | f0.y | f0.z | f0.w | f1.x | f1.y | f1.z | f1.w
                       | f2.x | f2.y | f2.z | f2.w | f3.x | f3.y | f3.z | f3.w;
    const bool hasT2 = flags & 1u, hasP2 = flags & 2u;
    const bool hasT3 = flags & 4u, hasP3 = flags & 8u;

    // ---- Phase 3: independent per-position multipliers ----
    float acc = 0.0f;
    P3(0, ce0); P3(1, ce1); P3(2, ce2); P3(3, ce3);
    P3(4, ce4); P3(5, ce5); P3(6, ce6); P3(7, ce7);

    // ---- Reduce to per-row partial ----
    double dacc = (double)acc;
    #pragma unroll
    for (int o = 32; o > 0; o >>= 1) dacc += __shfl_down(dacc, o);
    if (lane == 0) { s_red[wid] = dacc; s_redc[wid] = cntw; }
    __syncthreads();
    if (tid == 0) {
        double tot = 0.0; unsigned int c = 0;
        #pragma unroll
        for (int i = 0; i < 16; ++i) { tot += s_red[i]; c += (unsigned int)s_redc[i]; }
        psum[row] = tot;
        pcnt[row] = c;
    }
}

__global__ __launch_bounds__(512) void finalize_kernel(
    const double* __restrict__ psum, const unsigned int* __restrict__ pcnt,
    float* __restrict__ out)
{
    __shared__ double       sd[8];
    __shared__ unsigned int sc[8];
    int tid = threadIdx.x, lane = tid & 63, wid = tid >> 6;
    double v = psum[tid];
    unsigned int c = pcnt[tid];
    #pragma unroll
    for (int o = 32; o > 0; o >>= 1) {
        v += __shfl_down(v, o);
        c += __shfl_down(c, o);
    }
    if (lane == 0) { sd[wid] = v; sc[wid] = c; }
    __syncthreads();
    if (tid == 0) {
        double t = 0.0; unsigned int cc = 0;
        #pragma unroll
        for (int i = 0; i < 8; ++i) { t += sd[i]; cc += sc[i]; }
        double d = (cc > 0u) ? (double)cc : 1.0;
        out[0] = (float)(t / d);
    }
}

extern "C" void kernel_launch(void* const* d_in, const int* in_sizes, int n_in,
                              void* d_out, int out_size, void* d_ws, size_t ws_size,
                              hipStream_t stream) {
    const float* logits = (const float*)d_in[0];
    const int*   labels = (const int*)d_in[1];
    float* out = (float*)d_out;
    double* psum = (double*)d_ws;
    unsigned int* pcnt = (unsigned int*)(psum + BROWS);

    row_loss_kernel<<<BROWS, NT, 0, stream>>>(logits, labels, psum, pcnt);
    finalize_kernel<<<1, 512, 0, stream>>>(psum, pcnt, out);
}

// Round 7
// 117.492 us; speedup vs baseline: 1.0806x; 1.0806x over previous
//
#include <hip/hip_runtime.h>
#include <math.h>

#define BROWS 512
#define SLEN  8192
#define HALF  4096
#define NT    1024             // threads per block (16 waves)
#define NBLK  (BROWS * 2)      // 2 blocks per row
#define LH    256              // left halo (carry safety + window)
#define RH    64               // right halo (window)
#define EXTP  (LH + HALF + RH) // 4416 extended positions
#define EWRD  (EXTP / 32)      // 138 mask words
#define MW    (EWRD + 2)       // +1 guard word each side (window masks)

// distance (capped; >5 -> 99) to nearest set bit within +/-5 of ext-position e
__device__ __forceinline__ int win_dist(const unsigned int* __restrict__ M, int e) {
    int sI = e + 27;                   // (e-5) + 32-bit guard offset
    int w  = sI >> 5;
    int off = sI & 31;
    unsigned long long val =
        ((unsigned long long)M[w] | ((unsigned long long)M[w + 1] << 32)) >> off;
    unsigned int win = (unsigned int)val & 0x7FFu;   // bit5 == position e
    if (win & 32u) return 0;
    unsigned int dn = win & 31u;
    unsigned int up = (win >> 6) & 31u;
    int d = 99;
    if (dn) d = 5 - (31 - __clz((int)dn));
    if (up) { int du = __ffs((int)up); if (du < d) d = du; }
    return d;
}

__device__ __forceinline__ float decay_pow(int d) {
    return (d == 1) ? 0.7f : (d == 2) ? 0.49f : (d == 3) ? 0.343f
         : (d == 4) ? 0.2401f : 0.16807f;
}

// ---- main-step: argmax + CE + pack + ballot-publish (ext = LH + k*NT + tid) ----
#define STEP(k, qv, lab, cev) {                                               \
    float m01 = fmaxf((qv).x, (qv).y), m23 = fmaxf((qv).z, (qv).w);           \
    float best = fmaxf(m01, m23);                                             \
    int pred = (best == (qv).x) ? 0 : (best == (qv).y) ? 1                    \
             : (best == (qv).z) ? 2 : 3;                                      \
    bool valid = ((lab) != -100);                                             \
    int l = valid ? ((lab) & 3) : 0;                                          \
    float se = __expf((qv).x - best) + __expf((qv).y - best) +                \
               __expf((qv).z - best) + __expf((qv).w - best);                 \
    float lse = best + __logf(se);                                            \
    float xl = (l == 0) ? (qv).x : (l == 1) ? (qv).y                          \
             : (l == 2) ? (qv).z : (qv).w;                                    \
    cev = valid ? (lse - xl) * ((l >= 2) ? 30.0f : 1.0f) : 0.0f;              \
    pk32 |= (unsigned)(pred | (l << 2) | (valid ? 16 : 0)) << (8 * (k));      \
    unsigned long long bT2 = __ballot(valid && l == 2);                       \
    unsigned long long bP2 = __ballot(pred == 2);                             \
    unsigned long long bT3 = __ballot(valid && l == 3);                       \
    unsigned long long bP3 = __ballot(pred == 3);                             \
    unsigned long long bV  = __ballot(valid);                                 \
    unsigned long long bPM = __ballot(valid && (pred & 1));                   \
    unsigned long long bTM = __ballot(valid && (l & 1));                      \
    int wk = (LH + (k) * NT + (wid << 6)) >> 5;                               \
    if (lane == 0) {                                                          \
        s_m[0][1 + wk] = (unsigned)bT2; s_m[1][1 + wk] = (unsigned)bP2;       \
        s_m[2][1 + wk] = (unsigned)bT3; s_m[3][1 + wk] = (unsigned)bP3;       \
        s_v[wk] = (unsigned)bV; s_pm[wk] = (unsigned)bPM;                     \
        s_tm[wk] = (unsigned)bTM;                                             \
    } else if (lane == 32) {                                                  \
        s_m[0][2 + wk] = (unsigned)(bT2 >> 32);                               \
        s_m[1][2 + wk] = (unsigned)(bP2 >> 32);                               \
        s_m[2][2 + wk] = (unsigned)(bT3 >> 32);                               \
        s_m[3][2 + wk] = (unsigned)(bP3 >> 32);                               \
        s_v[wk + 1] = (unsigned)(bV >> 32);                                   \
        s_pm[wk + 1] = (unsigned)(bPM >> 32);                                 \
        s_tm[wk + 1] = (unsigned)(bTM >> 32);                                 \
    }                                                                         \
    fl |= (bT2 ? 1u : 0u) | (bP2 ? 2u : 0u) | (bT3 ? 4u : 0u)                 \
        | (bP3 ? 8u : 0u);                                                    \
    cntw += (int)__popcll(bV);                                                \
}

// ---- phase-3: random-access carry lookup + window multipliers (ext space) ----
#define P3(k, cev) {                                                          \
    int ext = LH + (k) * NT + tid;                                            \
    unsigned pk = (pk32 >> (8 * (k))) & 31u;                                  \
    int pred = pk & 3, l = (pk >> 2) & 3;                                     \
    bool valid = (pk & 16) != 0;                                              \
    float m = 1.0f;                                                           \
    if (valid && (pred >= 2 || l >= 2)) {                                     \
        int w = ext >> 5, b = ext & 31;                                       \
        unsigned hi = s_v[w];                                                 \
        unsigned lo = (w > 0) ? s_v[w - 1] : 0u;                              \
        unsigned long long x = (((unsigned long long)hi) << 32) | lo;         \
        x &= (1ull << (b + 32)) - 1ull;                                       \
        int pm = 0, tm = 0;                                                   \
        if (x) {                                                              \
            int p = 63 - __clzll(x);                                          \
            int ww = w - 1 + (p >> 5); int pb = p & 31;                       \
            pm = (int)((s_pm[ww] >> pb) & 1u);                                \
            tm = (int)((s_tm[ww] >> pb) & 1u);                                \
        } else if (w >= 2) {      /* >=32-long invalid run: ~never */         \
            int ww = w - 2; unsigned xx = 0u;                                 \
            while (ww >= 0 && (xx = s_v[ww]) == 0u) --ww;                     \
            if (ww >= 0) { int pb = 31 - __clz((int)xx);                      \
                pm = (int)((s_pm[ww] >> pb) & 1u);                            \
                tm = (int)((s_tm[ww] >> pb) & 1u); }                          \
        }                                                                     \
        bool bad = (pred == 2 && pm == 0) || (pred == 3 && pm == 1);          \
        if (bad) m *= 100.0f;                                                 \
        bool good = (l == 2 && tm == 1 && pred == 2) ||                       \
                    (l == 3 && tm == 0 && pred == 3);                         \
        if (good) m *= 0.1f;                                                  \
    }                                                                         \
    if (pred >= 2) {                                                          \
        bool has = (pred == 2) ? hasT2 : hasT3;                               \
        if (!has) m *= 20.0f;                                                 \
        else {                                                                \
            int d = win_dist(s_m[(pred - 2) << 1], ext);                      \
            m *= (d == 0) ? 0.1f : (d <= 5) ? decay_pow(d) : 10.0f;           \
        }                                                                     \
    }                                                                         \
    if (valid && l >= 2) {                                                    \
        bool has = (l == 2) ? hasP2 : hasP3;                                  \
        if (!has) m *= 3.0f;                                                  \
        else if (win_dist(s_m[1 + ((l - 2) << 1)], ext) > 5) m *= 2.0f;       \
    }                                                                         \
    acc += (cev) * m;                                                         \
}

__global__ __launch_bounds__(NT, 4) void row_loss_kernel(
    const float* __restrict__ logits, const int* __restrict__ labels,
    double* __restrict__ psum, unsigned int* __restrict__ pcnt)
{
    __shared__ unsigned int s_m[4][MW];     // window masks over ext range
    __shared__ unsigned int s_v[EWRD];      // valid bitmask (ext)
    __shared__ unsigned int s_pm[EWRD];     // valid & (pred&1)
    __shared__ unsigned int s_tm[EWRD];     // valid & (lab&1)
    __shared__ unsigned int s_wfl[16];
    __shared__ double       s_red[16];
    __shared__ int          s_redc[16];

    const int row   = blockIdx.x >> 1;
    const int half  = blockIdx.x & 1;
    const int start = half * HALF;
    const int tid   = threadIdx.x;
    const int lane  = tid & 63;
    const int wid   = tid >> 6;

    if (tid < 4) { s_m[tid][0] = 0u; s_m[tid][MW - 1] = 0u; }

    const float4* lg4 = (const float4*)logits + (size_t)row * SLEN;
    const int*    lb  = labels + (size_t)row * SLEN;

    // ---- main loads (coalesced, t = start + k*NT + tid) ----
    float4 q0 = lg4[start + 0 * NT + tid], q1 = lg4[start + 1 * NT + tid];
    float4 q2 = lg4[start + 2 * NT + tid], q3 = lg4[start + 3 * NT + tid];
    int la0 = lb[start + 0 * NT + tid], la1 = lb[start + 1 * NT + tid];
    int la2 = lb[start + 2 * NT + tid], la3 = lb[start + 3 * NT + tid];

    unsigned int pk32 = 0u, fl = 0u;
    int cntw = 0;
    float ce0, ce1, ce2, ce3;

    // ---- exact row-global hasT2/hasT3: read the other half's labels ----
    {
        const int ostart = (1 - half) * HALF;
        int4 ol = *(const int4*)(lb + ostart + tid * 4);
        bool a2 = (ol.x == 2) | (ol.y == 2) | (ol.z == 2) | (ol.w == 2);
        bool a3 = (ol.x == 3) | (ol.y == 3) | (ol.z == 3) | (ol.w == 3);
        unsigned long long b2 = __ballot(a2), b3 = __ballot(a3);
        fl |= (b2 ? 1u : 0u) | (b3 ? 4u : 0u);
    }

    // ---- halo: waves 0..4 publish masks for ext [0,LH) and [LH+HALF, EXTP) ----
    if (wid < 5) {
        bool isL = tid < LH;
        bool exists = isL ? (half == 1) : (half == 0);
        int gt = isL ? (start - LH + tid) : (start + HALF + (tid - LH));
        int gcl = exists ? gt : 0;
        float4 v = lg4[gcl];
        int lab = exists ? lb[gcl] : -100;
        float m01 = fmaxf(v.x, v.y), m23 = fmaxf(v.z, v.w);
        float best = fmaxf(m01, m23);
        int pred = (best == v.x) ? 0 : (best == v.y) ? 1 : (best == v.z) ? 2 : 3;
        bool valid = exists && (lab != -100);
        int l = valid ? (lab & 3) : 0;
        unsigned long long bT2 = __ballot(valid && l == 2);
        unsigned long long bP2 = __ballot(exists && pred == 2);
        unsigned long long bT3 = __ballot(valid && l == 3);
        unsigned long long bP3 = __ballot(exists && pred == 3);
        unsigned long long bV  = __ballot(valid);
        unsigned long long bPM = __ballot(valid && (pred & 1));
        unsigned long long bTM = __ballot(valid && (l & 1));
        int ext0 = isL ? (wid << 6) : (HALF + LH);   // wave-uniform base
        int wk = ext0 >> 5;
        if (lane == 0) {
            s_m[0][1 + wk] = (unsigned)bT2; s_m[1][1 + wk] = (unsigned)bP2;
            s_m[2][1 + wk] = (unsigned)bT3; s_m[3][1 + wk] = (unsigned)bP3;
            s_v[wk] = (unsigned)bV; s_pm[wk] = (unsigned)bPM;
            s_tm[wk] = (unsigned)bTM;
        } else if (lane == 32) {
            s_m[0][2 + wk] = (unsigned)(bT2 >> 32);
            s_m[1][2 + wk] = (unsigned)(bP2 >> 32);
            s_m[2][2 + wk] = (unsigned)(bT3 >> 32);
            s_m[3][2 + wk] = (unsigned)(bP3 >> 32);
            s_v[wk + 1] = (unsigned)(bV >> 32);
            s_pm[wk + 1] = (unsigned)(bPM >> 32);
            s_tm[wk + 1] = (unsigned)(bTM >> 32);
        }
        fl |= (bT2 ? 1u : 0u) | (bP2 ? 2u : 0u) | (bT3 ? 4u : 0u)
            | (bP3 ? 8u : 0u);
    }

    // ---- main phase 1 ----
    STEP(0, q0, la0, ce0); STEP(1, q1, la1, ce1);
    STEP(2, q2, la2, ce2); STEP(3, q3, la3, ce3);

    if (lane == 0) s_wfl[wid] = fl;
    __syncthreads();   // all masks + flags visible

    uint4 f0 = *(const uint4*)(s_wfl + 0), f1 = *(const uint4*)(s_wfl + 4);
    uint4 f2 = *(const uint4*)(s_wfl + 8), f3 = *(const uint4*)(s_wfl + 12);
    unsigned int flags = f0.x | f0.y | f0.z | f0.w | f1.x | f1.y | f1.z | f1.w
                       | f2.x | f2.y | f2.z | f2.w | f3.x | f3.y | f3.z | f3.w;
    const bool hasT2 = flags & 1u, hasP2 = flags & 2u;
    const bool hasT3 = flags & 4u, hasP3 = flags & 8u;

    // ---- phase 3 ----
    float acc = 0.0f;
    P3(0, ce0); P3(1, ce1); P3(2, ce2); P3(3, ce3);

    // ---- reduce to per-block partial ----
    double dacc = (double)acc;
    #pragma unroll
    for (int o = 32; o > 0; o >>= 1) dacc += __shfl_down(dacc, o);
    if (lane == 0) { s_red[wid] = dacc; s_redc[wid] = cntw; }
    __syncthreads();
    if (tid == 0) {
        double tot = 0.0; unsigned int c = 0;
        #pragma unroll
        for (int i = 0; i < 16; ++i) { tot += s_red[i]; c += (unsigned int)s_redc[i]; }
        psum[blockIdx.x] = tot;
        pcnt[blockIdx.x] = c;
    }
}

__global__ __launch_bounds__(NT) void finalize_kernel(
    const double* __restrict__ psum, const unsigned int* __restrict__ pcnt,
    float* __restrict__ out)
{
    __shared__ double       sd[16];
    __shared__ unsigned int sc[16];
    int tid = threadIdx.x, lane = tid & 63, wid = tid >> 6;
    double v = psum[tid];
    unsigned int c = pcnt[tid];
    #pragma unroll
    for (int o = 32; o > 0; o >>= 1) {
        v += __shfl_down(v, o);
        c += __shfl_down(c, o);
    }
    if (lane == 0) { sd[wid] = v; sc[wid] = c; }
    __syncthreads();
    if (tid == 0) {
        double t = 0.0; unsigned int cc = 0;
        #pragma unroll
        for (int i = 0; i < 16; ++i) { t += sd[i]; cc += sc[i]; }
        double d = (cc > 0u) ? (double)cc : 1.0;
        out[0] = (float)(t / d);
    }
}

extern "C" void kernel_launch(void* const* d_in, const int* in_sizes, int n_in,
                              void* d_out, int out_size, void* d_ws, size_t ws_size,
                              hipStream_t stream) {
    const float* logits = (const float*)d_in[0];
    const int*   labels = (const int*)d_in[1];
    float* out = (float*)d_out;
    double* psum = (double*)d_ws;
    unsigned int* pcnt = (unsigned int*)(psum + NBLK);

    row_loss_kernel<<<NBLK, NT, 0, stream>>>(logits, labels, psum, pcnt);
    finalize_kernel<<<1, NT, 0, stream>>>(psum, pcnt, out);
}